// Round 7
// baseline (314.236 us; speedup 1.0000x reference)
//
#include <hip/hip_runtime.h>
#include <math.h>

typedef _Float16 Hh;
typedef __attribute__((ext_vector_type(8))) _Float16 half8;
typedef __attribute__((ext_vector_type(4))) _Float16 half4;
typedef __attribute__((ext_vector_type(4))) float float4v;

#define B_ 2
#define H_ 16
#define N_ 2048
#define D_ 64
#define ND_ (N_*D_)
#define C1 0.04508422f   // (1/32)*log2(e); softmax in base-2 throughout

// Ebuf: [j(32)][i(32)][f(16+4pad)]  j-stride 644, i-stride 20 halves
#define EB_JS 644
#define EB_IS 20
// Pm: [e(16)][i(32)][j(32+4pad)]    e-stride 1156, i-stride 36 halves
#define PM_ES 1156
#define PM_IS 36

// ---------------------------------------------------------------------------
// K1: prep. (unchanged from R6 — passing)
//  blocks [0,512):  premix q,k with W_pre -> f16 qb/kb [b][e][n][d]
//  blocks [512,768): transpose v -> f16 vt2, tile-blocked [be][jt][d][j&31]
// ---------------------------------------------------------------------------
__global__ __launch_bounds__(256) void prep_kernel(const float* __restrict__ q,
    const float* __restrict__ k, const float* __restrict__ v,
    const float* __restrict__ Wpre,
    Hh* __restrict__ qb, Hh* __restrict__ kb, Hh* __restrict__ vt2)
{
    int tid = threadIdx.x;
    int bid = blockIdx.x;
    if (bid < 512) {
        __shared__ float wsh[256];
        wsh[tid] = Wpre[tid];
        __syncthreads();
        int tensor = bid >> 8;
        int g = ((bid & 255) << 8) | tid;     // 0 .. 65535
        int b = g >> 15;
        int r = g & 32767;                    // (n,d4): n*16 + d4
        const float4* src = (const float4*)(tensor ? k : q);
        Hh* dst = tensor ? kb : qb;
        float4 x[16];
        #pragma unroll
        for (int f=0; f<16; f++) x[f] = src[(size_t)(b*16+f)*32768 + r];
        #pragma unroll
        for (int e=0; e<16; e++) {
            float4 a = make_float4(0.f,0.f,0.f,0.f);
            #pragma unroll
            for (int f=0; f<16; f++) {
                float wv = wsh[e*16+f];
                a.x += wv*x[f].x; a.y += wv*x[f].y; a.z += wv*x[f].z; a.w += wv*x[f].w;
            }
            half4 hv; hv[0]=(Hh)a.x; hv[1]=(Hh)a.y; hv[2]=(Hh)a.z; hv[3]=(Hh)a.w;
            *(half4*)(dst + (size_t)(b*16+e)*ND_ + (size_t)r*4) = hv;
        }
    } else {
        __shared__ Hh tile[64*48];            // [d][j], stride 48 halves
        int tb = bid - 512;                   // 0..255
        int be = tb >> 3;                     // 0..31
        int jtg = tb & 7;
        const float4* v4 = (const float4*)v;
        for (int u=0; u<8; u++) {
            int jt = jtg*8 + u;               // 0..63
            #pragma unroll
            for (int p=0; p<2; p++) {
                int j = p*16 + (tid>>4);
                int d4 = tid & 15;
                float4 val = v4[(size_t)be*32768 + (size_t)(jt*32+j)*16 + d4];
                tile[(d4*4+0)*48 + j] = (Hh)val.x;
                tile[(d4*4+1)*48 + j] = (Hh)val.y;
                tile[(d4*4+2)*48 + j] = (Hh)val.z;
                tile[(d4*4+3)*48 + j] = (Hh)val.w;
            }
            __syncthreads();
            {
                int d = tid >> 2;
                int jc = (tid & 3) * 8;
                half8 o;
                #pragma unroll
                for (int z=0; z<8; z++) o[z] = tile[d*48 + jc + z];
                *(half8*)(vt2 + ((size_t)(be*64) + jt)*2048 + (size_t)tid*8) = o;
            }
            __syncthreads();
        }
    }
}

// ---------------------------------------------------------------------------
// K2: denominators. LDS-free, barrier-free. i-tile 64 (4 ig) halves K traffic
// vs R6. 512 thr / 8 waves; wave w owns f={2w,2w+1}; slabs jt ≡ s (mod 8).
// ---------------------------------------------------------------------------
__global__ __launch_bounds__(512) void denom_kernel(const Hh* __restrict__ qb,
    const Hh* __restrict__ kb, float* __restrict__ lacc_g)
{
    int bid = blockIdx.x;
    int s = bid & 7;
    int idx = 63 - (bid >> 3);
    int b = idx & 1, it = idx >> 1;          // it 0..31
    int jtmax = 2*it + 1;
    if (s > jtmax) return;
    int i0 = it * 64;

    int tid = threadIdx.x;
    int lane = tid & 63, w = tid >> 6;
    int qd = lane >> 4, c = lane & 15;
    int f0 = 2*w;

    half8 aq[2][4][2];
    #pragma unroll
    for (int fi=0; fi<2; fi++) {
        #pragma unroll
        for (int ig=0; ig<4; ig++) {
            const Hh* qr = qb + (size_t)((b*16+f0+fi)*N_ + i0 + ig*16 + c)*64 + qd*8;
            aq[fi][ig][0] = *(const half8*)qr;
            aq[fi][ig][1] = *(const half8*)(qr+32);
        }
    }
    float lacc[2][4][4];
    #pragma unroll
    for (int fi=0;fi<2;fi++) for (int ig=0;ig<4;ig++) for (int r=0;r<4;r++) lacc[fi][ig][r]=0.f;

    for (int jt = s; jt <= jtmax; jt += 8) {
        int j0 = jt*32;
        #pragma unroll
        for (int fi=0; fi<2; fi++) {
            #pragma unroll
            for (int jh=0; jh<2; jh++) {
                const Hh* kr = kb + (size_t)((b*16+f0+fi)*N_ + j0 + jh*16 + c)*64 + qd*8;
                half8 b0 = *(const half8*)kr;
                half8 b1 = *(const half8*)(kr+32);
                #pragma unroll
                for (int ig=0; ig<4; ig++) {
                    float4v sv = {0.f,0.f,0.f,0.f};
                    sv = __builtin_amdgcn_mfma_f32_16x16x32_f16(aq[fi][ig][0], b0, sv, 0,0,0);
                    sv = __builtin_amdgcn_mfma_f32_16x16x32_f16(aq[fi][ig][1], b1, sv, 0,0,0);
                    #pragma unroll
                    for (int r=0; r<4; r++) {
                        int i = i0 + ig*16 + qd*4 + r;
                        int j = j0 + jh*16 + c;
                        float ev = (j <= i) ? __builtin_amdgcn_exp2f(sv[r]*C1) : 0.f;
                        lacc[fi][ig][r] += ev;
                    }
                }
            }
        }
    }
    #pragma unroll
    for (int fi=0; fi<2; fi++) {
        #pragma unroll
        for (int ig=0; ig<4; ig++) {
            #pragma unroll
            for (int r=0; r<4; r++) {
                float vs = lacc[fi][ig][r];
                vs += __shfl_xor(vs, 1);
                vs += __shfl_xor(vs, 2);
                vs += __shfl_xor(vs, 4);
                vs += __shfl_xor(vs, 8);
                if (c == 0)
                    unsafeAtomicAdd(&lacc_g[(size_t)(b*16+f0+fi)*N_ + i0 + ig*16 + qd*4 + r], vs);
            }
        }
    }
}

// ---------------------------------------------------------------------------
// K3: main fused pass. i-tile 32 (halves K/V traffic/row vs R6). 512 thr /
// 8 waves; j-tile 32, slabs jt ≡ s (mod 4). Roles:
//  scores: wave (ig=w>>2, fg=w&3): f=4fg..4fg+3, i-half ig, both jh.
//  mix:    wave w: i-quad 4w, both jh (16x16x16, A=E, B=W^T in regs).
//  PV:     wave (ig=w>>2, eg=w&3): e=4eg..4eg+3, K=32 MFMA, V direct global.
// Loop: [mix; bar; PV + scores(t+4); bar]. LDS 78.2 KB -> 1 block/CU.
// ---------------------------------------------------------------------------
__global__ __launch_bounds__(512,2) void attend_kernel(const Hh* __restrict__ qb,
    const Hh* __restrict__ kb, const Hh* __restrict__ vt2,
    const float* __restrict__ lacc_g, const float* __restrict__ Wpost,
    float* __restrict__ out)
{
    __shared__ Hh Ebuf[32*EB_JS];   // 41216 B
    __shared__ Hh Pm[16*PM_ES];     // 36992 B

    int bid = blockIdx.x;
    int s = bid & 3;
    int idx = 127 - (bid >> 2);
    int b = idx & 1, it = idx >> 1;          // it 0..63 (32-row tiles)
    if (s > it) return;                       // jtmax = it
    int i0 = it * 32;
    int jtmax = it;

    int tid = threadIdx.x;
    int lane = tid & 63, w = tid >> 6;
    int qd = lane >> 4, c = lane & 15;
    int ig = w >> 2;                          // i-half for scores & PV
    int fg = w & 3;                           // f-group for scores
    int fb = fg * 4;

    // Q A-frags (rows i0+ig*16+c) + log2-denominators
    half8 aq[4][2];
    float lgr[4][4];
    #pragma unroll
    for (int ff=0; ff<4; ff++) {
        int f = fb + ff;
        const Hh* qr = qb + (size_t)((b*16+f)*N_ + i0 + ig*16 + c)*64 + qd*8;
        aq[ff][0] = *(const half8*)qr;
        aq[ff][1] = *(const half8*)(qr+32);
        #pragma unroll
        for (int r=0; r<4; r++)
            lgr[ff][r] = __builtin_amdgcn_logf(
                lacc_g[(size_t)(b*16+f)*N_ + i0 + ig*16 + qd*4 + r]);
    }
    // W_post B-frag (16x16x16): B[k=f=qd*4+z][n=e=c]
    half4 wf;
    #pragma unroll
    for (int z=0; z<4; z++) wf[z] = (Hh)Wpost[c*16 + qd*4 + z];

    float4v acc[4][4];
    #pragma unroll
    for (int el=0; el<4; el++) for (int nc=0; nc<4; nc++)
        acc[el][nc] = (float4v){0.f,0.f,0.f,0.f};

    auto scores = [&](int jt) {
        int j0 = jt*32;
        half8 kr0[4][2], kr1[4][2];
        #pragma unroll
        for (int ff=0; ff<4; ff++) {
            #pragma unroll
            for (int jh=0; jh<2; jh++) {
                const Hh* kr = kb + (size_t)((b*16+fb+ff)*N_ + j0 + jh*16 + c)*64 + qd*8;
                kr0[ff][jh] = *(const half8*)kr;
                kr1[ff][jh] = *(const half8*)(kr+32);
            }
        }
        float4v sv[4][2];
        #pragma unroll
        for (int ff=0; ff<4; ff++) {
            #pragma unroll
            for (int jh=0; jh<2; jh++) {
                float4v t = {0.f,0.f,0.f,0.f};
                t = __builtin_amdgcn_mfma_f32_16x16x32_f16(aq[ff][0], kr0[ff][jh], t, 0,0,0);
                t = __builtin_amdgcn_mfma_f32_16x16x32_f16(aq[ff][1], kr1[ff][jh], t, 0,0,0);
                sv[ff][jh] = t;
            }
        }
        #pragma unroll
        for (int jh=0; jh<2; jh++) {
            #pragma unroll
            for (int r=0; r<4; r++) {
                int i = i0 + ig*16 + qd*4 + r;
                int j = j0 + jh*16 + c;
                half4 h;
                #pragma unroll
                for (int ff=0; ff<4; ff++)
                    h[ff] = (Hh)((j <= i) ? __builtin_amdgcn_exp2f(sv[ff][jh][r]*C1 - lgr[ff][r]) : 0.f);
                *(half4*)&Ebuf[(jh*16+c)*EB_JS + (ig*16+qd*4+r)*EB_IS + fb] = h;
            }
        }
    };

    scores(s);
    __syncthreads();

    for (int jt = s; jt <= jtmax; jt += 4) {
        // ---- head mix: wave w owns i-quad 4w, both jh halves ----
        #pragma unroll
        for (int jh2=0; jh2<2; jh2++) {
            #pragma unroll
            for (int ii=0; ii<4; ii++) {
                int i = 4*w + ii;
                half4 ef = *(const half4*)&Ebuf[(jh2*16+c)*EB_JS + i*EB_IS + qd*4];
                float4v cc = {0.f,0.f,0.f,0.f};
                cc = __builtin_amdgcn_mfma_f32_16x16x16f16(ef, wf, cc, 0,0,0);
                half4 hv;
                #pragma unroll
                for (int r=0; r<4; r++) hv[r] = (Hh)cc[r];
                *(half4*)&Pm[c*PM_ES + i*PM_IS + jh2*16 + qd*4] = hv;
            }
        }
        __syncthreads();
        // ---- PV(jt): wave (ig, eg): e = 4*eg..4*eg+3 ----
        #pragma unroll
        for (int el=0; el<4; el++) {
            int e = fg*4 + el;   // fg == w&3 doubles as e-group
            half8 pa = *(const half8*)&Pm[e*PM_ES + (ig*16+c)*PM_IS + qd*8];
            #pragma unroll
            for (int nc=0; nc<4; nc++) {
                const Hh* vr = vt2 + (size_t)((b*16+e)*64 + jt)*2048 + (nc*16+c)*32 + qd*8;
                half8 vb = *(const half8*)vr;
                acc[el][nc] = __builtin_amdgcn_mfma_f32_16x16x32_f16(pa, vb, acc[el][nc], 0,0,0);
            }
        }
        if (jt + 4 <= jtmax) scores(jt + 4);
        __syncthreads();
    }

    // ---- accumulate partial O: D[m=i][n=d] ----
    #pragma unroll
    for (int el=0; el<4; el++) {
        int e = fg*4 + el;
        #pragma unroll
        for (int nc=0; nc<4; nc++) {
            #pragma unroll
            for (int r=0; r<4; r++)
                unsafeAtomicAdd(&out[(size_t)((b*16+e)*N_ + i0 + ig*16 + qd*4 + r)*64 + nc*16 + c],
                                acc[el][nc][r]);
        }
    }
}

extern "C" void kernel_launch(void* const* d_in, const int* in_sizes, int n_in,
                              void* d_out, int out_size, void* d_ws, size_t ws_size,
                              hipStream_t stream) {
    const float* q     = (const float*)d_in[0];
    const float* k     = (const float*)d_in[1];
    const float* v     = (const float*)d_in[2];
    const float* Wpre  = (const float*)d_in[3];
    const float* Wpost = (const float*)d_in[4];
    float* out = (float*)d_out;

    size_t tsz = (size_t)B_*H_*N_*D_;       // 4 Mi halves = 8 MB each
    Hh* qb = (Hh*)d_ws;
    Hh* kb = qb + tsz;
    Hh* vt2 = kb + tsz;
    float* lacc = (float*)(vt2 + tsz);      // 24 MB offset, 256 KB

    hipMemsetAsync(lacc, 0, (size_t)B_*H_*N_*sizeof(float), stream);
    hipMemsetAsync(out, 0, (size_t)out_size*sizeof(float), stream);
    prep_kernel<<<768, 256, 0, stream>>>(q, k, v, Wpre, qb, kb, vt2);
    denom_kernel<<<512, 512, 0, stream>>>(qb, kb, lacc);
    attend_kernel<<<512, 512, 0, stream>>>(qb, kb, vt2, lacc, Wpost, out);
}

// Round 8
// 309.049 us; speedup vs baseline: 1.0168x; 1.0168x over previous
//
#include <hip/hip_runtime.h>
#include <math.h>

typedef _Float16 Hh;
typedef __attribute__((ext_vector_type(8))) _Float16 half8;
typedef __attribute__((ext_vector_type(4))) _Float16 half4;
typedef __attribute__((ext_vector_type(4))) float float4v;

#define B_ 2
#define H_ 16
#define N_ 2048
#define D_ 64
#define ND_ (N_*D_)
#define C1 0.04508422f   // (1/32)*log2(e); softmax in base-2 throughout

// Ebuf: [j(32)][i(16)][f(16+4pad)]  j-stride 324, i-stride 20 halves
#define EB_JS 324
#define EB_IS 20
// Pm: [e(16)][i(16)][j(32+4pad)]    e-stride 580, i-stride 36 halves
#define PM_ES 580
#define PM_IS 36

// ---------------------------------------------------------------------------
// K1: prep.
//  blocks [0,512):    premix q,k with W_pre -> f16 qb/kb [b][e][n][d]
//  blocks [512,768):  transpose v -> f16 vt2, tile-blocked [be][jt][d][j&31]
//  blocks [768,1792): zero out (16.8 MB) and lacc (256 KB) — replaces memsets
// ---------------------------------------------------------------------------
__global__ __launch_bounds__(256) void prep_kernel(const float* __restrict__ q,
    const float* __restrict__ k, const float* __restrict__ v,
    const float* __restrict__ Wpre,
    Hh* __restrict__ qb, Hh* __restrict__ kb, Hh* __restrict__ vt2,
    float4* __restrict__ out4, float4* __restrict__ lacc4)
{
    int tid = threadIdx.x;
    int bid = blockIdx.x;
    if (bid < 512) {
        __shared__ float wsh[256];
        wsh[tid] = Wpre[tid];
        __syncthreads();
        int tensor = bid >> 8;
        int g = ((bid & 255) << 8) | tid;     // 0 .. 65535
        int b = g >> 15;
        int r = g & 32767;                    // (n,d4): n*16 + d4
        const float4* src = (const float4*)(tensor ? k : q);
        Hh* dst = tensor ? kb : qb;
        float4 x[16];
        #pragma unroll
        for (int f=0; f<16; f++) x[f] = src[(size_t)(b*16+f)*32768 + r];
        #pragma unroll
        for (int e=0; e<16; e++) {
            float4 a = make_float4(0.f,0.f,0.f,0.f);
            #pragma unroll
            for (int f=0; f<16; f++) {
                float wv = wsh[e*16+f];
                a.x += wv*x[f].x; a.y += wv*x[f].y; a.z += wv*x[f].z; a.w += wv*x[f].w;
            }
            half4 hv; hv[0]=(Hh)a.x; hv[1]=(Hh)a.y; hv[2]=(Hh)a.z; hv[3]=(Hh)a.w;
            *(half4*)(dst + (size_t)(b*16+e)*ND_ + (size_t)r*4) = hv;
        }
    } else if (bid < 768) {
        __shared__ Hh tile[64*48];            // [d][j], stride 48 halves
        int tb = bid - 512;                   // 0..255
        int be = tb >> 3;                     // 0..31
        int jtg = tb & 7;
        const float4* v4 = (const float4*)v;
        for (int u=0; u<8; u++) {
            int jt = jtg*8 + u;               // 0..63
            #pragma unroll
            for (int p=0; p<2; p++) {
                int j = p*16 + (tid>>4);
                int d4 = tid & 15;
                float4 val = v4[(size_t)be*32768 + (size_t)(jt*32+j)*16 + d4];
                tile[(d4*4+0)*48 + j] = (Hh)val.x;
                tile[(d4*4+1)*48 + j] = (Hh)val.y;
                tile[(d4*4+2)*48 + j] = (Hh)val.z;
                tile[(d4*4+3)*48 + j] = (Hh)val.w;
            }
            __syncthreads();
            {
                int d = tid >> 2;
                int jc = (tid & 3) * 8;
                half8 o;
                #pragma unroll
                for (int z=0; z<8; z++) o[z] = tile[d*48 + jc + z];
                *(half8*)(vt2 + ((size_t)(be*64) + jt)*2048 + (size_t)tid*8) = o;
            }
            __syncthreads();
        }
    } else {
        // zero out + lacc. out = 2*16*2048*64 floats = 1048576 float4.
        int zid = (bid - 768) * 256 + tid;    // 0 .. 262143
        float4 zz = make_float4(0.f,0.f,0.f,0.f);
        #pragma unroll
        for (int u=0; u<4; u++) out4[(size_t)u*262144 + zid] = zz;
        if (zid < 16384) lacc4[zid] = zz;
    }
}

// ---------------------------------------------------------------------------
// K2: denominators. LDS-free, barrier-free, interleaved slabs (jt ≡ s mod 8).
// 512 thr / 8 waves; wave w owns f={2w,2w+1}; i-tile 32. (R6 verbatim)
// ---------------------------------------------------------------------------
__global__ __launch_bounds__(512) void denom_kernel(const Hh* __restrict__ qb,
    const Hh* __restrict__ kb, float* __restrict__ lacc_g)
{
    int bid = blockIdx.x;
    int s = bid & 7;
    int idx = 127 - (bid >> 3);
    int b = idx & 1, it = idx >> 1;          // it 0..63
    if (s > it) return;

    int i0 = it * 32;
    int tid = threadIdx.x;
    int lane = tid & 63, w = tid >> 6;
    int qd = lane >> 4, c = lane & 15;
    int f0 = 2*w;

    half8 aq[2][2][2];
    #pragma unroll
    for (int fi=0; fi<2; fi++) {
        #pragma unroll
        for (int ig=0; ig<2; ig++) {
            const Hh* qr = qb + (size_t)((b*16+f0+fi)*N_ + i0 + ig*16 + c)*64 + qd*8;
            aq[fi][ig][0] = *(const half8*)qr;
            aq[fi][ig][1] = *(const half8*)(qr+32);
        }
    }
    float lacc[2][2][4];
    #pragma unroll
    for (int fi=0;fi<2;fi++) for (int ig=0;ig<2;ig++) for (int r=0;r<4;r++) lacc[fi][ig][r]=0.f;

    for (int jt = s; jt <= it; jt += 8) {
        int j0 = jt*32;
        #pragma unroll
        for (int fi=0; fi<2; fi++) {
            #pragma unroll
            for (int jh=0; jh<2; jh++) {
                const Hh* kr = kb + (size_t)((b*16+f0+fi)*N_ + j0 + jh*16 + c)*64 + qd*8;
                half8 b0 = *(const half8*)kr;
                half8 b1 = *(const half8*)(kr+32);
                #pragma unroll
                for (int ig=0; ig<2; ig++) {
                    float4v sv = {0.f,0.f,0.f,0.f};
                    sv = __builtin_amdgcn_mfma_f32_16x16x32_f16(aq[fi][ig][0], b0, sv, 0,0,0);
                    sv = __builtin_amdgcn_mfma_f32_16x16x32_f16(aq[fi][ig][1], b1, sv, 0,0,0);
                    #pragma unroll
                    for (int r=0; r<4; r++) {
                        int i = i0 + ig*16 + qd*4 + r;
                        int j = j0 + jh*16 + c;
                        float ev = (j <= i) ? __builtin_amdgcn_exp2f(sv[r]*C1) : 0.f;
                        lacc[fi][ig][r] += ev;
                    }
                }
            }
        }
    }
    #pragma unroll
    for (int fi=0; fi<2; fi++) {
        #pragma unroll
        for (int ig=0; ig<2; ig++) {
            #pragma unroll
            for (int r=0; r<4; r++) {
                float vs = lacc[fi][ig][r];
                vs += __shfl_xor(vs, 1);
                vs += __shfl_xor(vs, 2);
                vs += __shfl_xor(vs, 4);
                vs += __shfl_xor(vs, 8);
                if (c == 0)
                    unsafeAtomicAdd(&lacc_g[(size_t)(b*16+f0+fi)*N_ + i0 + ig*16 + qd*4 + r], vs);
            }
        }
    }
}

// ---------------------------------------------------------------------------
// K3: main fused pass (R6 inner structure). 512 thr / 8 waves; i-tile 16,
// j-tile 32, slabs jt ≡ s (mod 8) -> 2048 blocks of <=8 iters, 4 blocks/CU
// resident (39.3 KB LDS), bid = idx*8+s puts slab s on XCD s (L2 locality).
//  scores: wave w -> f = 4*(w&3)..+3 at j-chunk jh=w>>2; E packed half4 over f.
//  mix:    Pm[j,e] = E[j,f]·Wpost^T; half4-over-j writes.
//  PV:     wave w -> e={2w,2w+1}; A=Pm b128 read, K=32 MFMA, V direct global.
// Loop: [mix; bar; PV + scores(t+8); bar].
// ---------------------------------------------------------------------------
__global__ __launch_bounds__(512,4) void attend_kernel(const Hh* __restrict__ qb,
    const Hh* __restrict__ kb, const Hh* __restrict__ vt2,
    const float* __restrict__ lacc_g, const float* __restrict__ Wpost,
    float* __restrict__ out)
{
    __shared__ Hh Ebuf[32*EB_JS];   // 20736 B
    __shared__ Hh Pm[16*PM_ES];     // 18560 B

    int bid = blockIdx.x;
    int s = bid & 7;
    int idx = 255 - (bid >> 3);
    int b = idx & 1, it = idx >> 1;          // it 0..127
    int jtmax = it >> 1;                     // last 32-j tile
    if (s > jtmax) return;
    int i0 = it * 16;

    int tid = threadIdx.x;
    int lane = tid & 63, w = tid >> 6;
    int qd = lane >> 4, c = lane & 15;

    // ---- scores role: wave w -> f-group fg=w&3 (f=4fg..4fg+3), j-chunk jh=w>>2
    int fg = w & 3, jh = w >> 2;
    half8 aq[4][2];
    float lgr[4][4];
    #pragma unroll
    for (int ff=0; ff<4; ff++) {
        int f = 4*fg + ff;
        const Hh* qr = qb + (size_t)((b*16+f)*N_ + i0 + c)*64 + qd*8;
        aq[ff][0] = *(const half8*)qr;
        aq[ff][1] = *(const half8*)(qr+32);
        #pragma unroll
        for (int r=0; r<4; r++)
            lgr[ff][r] = __builtin_amdgcn_logf(
                lacc_g[(size_t)(b*16+f)*N_ + i0 + qd*4 + r]);
    }
    // ---- mix role: wave w -> jh2=w&1, i in [4*(w>>1), +4)
    int jh2 = w & 1, ib = 4*(w>>1);
    half4 wf;   // B[k=f=qd*4+z][n=e=c] = Wpost[e][f]
    #pragma unroll
    for (int z=0; z<4; z++) wf[z] = (Hh)Wpost[c*16 + qd*4 + z];

    float4v acc[2][4];
    #pragma unroll
    for (int el=0; el<2; el++) for (int nc=0; nc<4; nc++)
        acc[el][nc] = (float4v){0.f,0.f,0.f,0.f};

    auto scores = [&](int jt) {
        int jc = jt*32 + jh*16;
        float4v sv[4];
        #pragma unroll
        for (int ff=0; ff<4; ff++) {
            int f = 4*fg + ff;
            const Hh* kr = kb + (size_t)((b*16+f)*N_ + jc + c)*64 + qd*8;
            half8 b0 = *(const half8*)kr;
            half8 b1 = *(const half8*)(kr+32);
            float4v t = {0.f,0.f,0.f,0.f};
            t = __builtin_amdgcn_mfma_f32_16x16x32_f16(aq[ff][0], b0, t, 0,0,0);
            t = __builtin_amdgcn_mfma_f32_16x16x32_f16(aq[ff][1], b1, t, 0,0,0);
            sv[ff] = t;
        }
        int j = jc + c;
        #pragma unroll
        for (int r=0; r<4; r++) {
            int i = i0 + qd*4 + r;
            half4 h;
            #pragma unroll
            for (int ff=0; ff<4; ff++)
                h[ff] = (Hh)((j <= i) ? __builtin_amdgcn_exp2f(sv[ff][r]*C1 - lgr[ff][r]) : 0.f);
            *(half4*)&Ebuf[(jh*16+c)*EB_JS + (qd*4+r)*EB_IS + fg*4] = h;
        }
    };

    scores(s);
    __syncthreads();

    for (int jt = s; jt <= jtmax; jt += 8) {
        // ---- head mix: Pm[j,e] for this wave's (jh2, i-quad) ----
        #pragma unroll
        for (int ii=0; ii<4; ii++) {
            int i = ib + ii;
            half4 ef = *(const half4*)&Ebuf[(jh2*16+c)*EB_JS + i*EB_IS + qd*4];
            float4v cc = {0.f,0.f,0.f,0.f};
            cc = __builtin_amdgcn_mfma_f32_16x16x16f16(ef, wf, cc, 0,0,0);
            // D[m=j=qd*4+r][n=e=c] -> pack half4 over j
            half4 hv;
            #pragma unroll
            for (int r=0; r<4; r++) hv[r] = (Hh)cc[r];
            *(half4*)&Pm[c*PM_ES + i*PM_IS + jh2*16 + qd*4] = hv;
        }
        __syncthreads();
        // ---- PV(jt), overlapped with scores(jt+8) ----
        #pragma unroll
        for (int el=0; el<2; el++) {
            int e = 2*w + el;
            half8 pa = *(const half8*)&Pm[e*PM_ES + c*PM_IS + qd*8];
            #pragma unroll
            for (int nc=0; nc<4; nc++) {
                const Hh* vr = vt2 + (size_t)((b*16+e)*64 + jt)*2048 + (nc*16+c)*32 + qd*8;
                half8 vb = *(const half8*)vr;
                acc[el][nc] = __builtin_amdgcn_mfma_f32_16x16x32_f16(pa, vb, acc[el][nc], 0,0,0);
            }
        }
        if (jt + 8 <= jtmax) scores(jt + 8);
        __syncthreads();
    }

    // ---- accumulate partial O: D[m=i][n=d], row=i0+qd*4+r, col d=nc*16+c ----
    #pragma unroll
    for (int el=0; el<2; el++) {
        int e = 2*w + el;
        #pragma unroll
        for (int nc=0; nc<4; nc++) {
            #pragma unroll
            for (int r=0; r<4; r++)
                unsafeAtomicAdd(&out[(size_t)((b*16+e)*N_ + i0 + qd*4 + r)*64 + nc*16 + c],
                                acc[el][nc][r]);
        }
    }
}

extern "C" void kernel_launch(void* const* d_in, const int* in_sizes, int n_in,
                              void* d_out, int out_size, void* d_ws, size_t ws_size,
                              hipStream_t stream) {
    const float* q     = (const float*)d_in[0];
    const float* k     = (const float*)d_in[1];
    const float* v     = (const float*)d_in[2];
    const float* Wpre  = (const float*)d_in[3];
    const float* Wpost = (const float*)d_in[4];
    float* out = (float*)d_out;

    size_t tsz = (size_t)B_*H_*N_*D_;       // 4 Mi halves = 8 MB each
    Hh* qb = (Hh*)d_ws;
    Hh* kb = qb + tsz;
    Hh* vt2 = kb + tsz;
    float* lacc = (float*)(vt2 + tsz);      // 24 MB offset, 256 KB

    prep_kernel<<<1792, 256, 0, stream>>>(q, k, v, Wpre, qb, kb, vt2,
                                          (float4*)out, (float4*)lacc);
    denom_kernel<<<1024, 512, 0, stream>>>(qb, kb, lacc);
    attend_kernel<<<2048, 512, 0, stream>>>(qb, kb, vt2, lacc, Wpost, out);
}

// Round 9
// 265.186 us; speedup vs baseline: 1.1850x; 1.1654x over previous
//
#include <hip/hip_runtime.h>
#include <math.h>

typedef _Float16 Hh;
typedef __attribute__((ext_vector_type(8))) _Float16 half8;
typedef __attribute__((ext_vector_type(4))) _Float16 half4;
typedef __attribute__((ext_vector_type(4))) float float4v;

#define B_ 2
#define H_ 16
#define N_ 2048
#define D_ 64
#define ND_ (N_*D_)
#define C1 0.04508422f   // (1/32)*log2(e); softmax in base-2 throughout

// Ebuf: [j(32)][i(16)][f(16+4pad)]  j-stride 324, i-stride 20 halves
#define EB_JS 324
#define EB_IS 20
// Pm: [e(16)][i(16)][j(32+4pad)]    e-stride 580, i-stride 36 halves
#define PM_ES 580
#define PM_IS 36

// ---------------------------------------------------------------------------
// K1: prep.
//  blocks [0,512):    premix q,k with W_pre -> f16 qb/kb [b][e][n][d]
//  blocks [512,768):  transpose v -> f16 vt2, tile-blocked [be][jt][d][j&31]
//  blocks [768,1792): zero out (16.8 MB) and lacc (256 KB) — replaces memsets
// ---------------------------------------------------------------------------
__global__ __launch_bounds__(256) void prep_kernel(const float* __restrict__ q,
    const float* __restrict__ k, const float* __restrict__ v,
    const float* __restrict__ Wpre,
    Hh* __restrict__ qb, Hh* __restrict__ kb, Hh* __restrict__ vt2,
    float4* __restrict__ out4, float4* __restrict__ lacc4)
{
    int tid = threadIdx.x;
    int bid = blockIdx.x;
    if (bid < 512) {
        __shared__ float wsh[256];
        wsh[tid] = Wpre[tid];
        __syncthreads();
        int tensor = bid >> 8;
        int g = ((bid & 255) << 8) | tid;     // 0 .. 65535
        int b = g >> 15;
        int r = g & 32767;                    // (n,d4): n*16 + d4
        const float4* src = (const float4*)(tensor ? k : q);
        Hh* dst = tensor ? kb : qb;
        float4 x[16];
        #pragma unroll
        for (int f=0; f<16; f++) x[f] = src[(size_t)(b*16+f)*32768 + r];
        #pragma unroll
        for (int e=0; e<16; e++) {
            float4 a = make_float4(0.f,0.f,0.f,0.f);
            #pragma unroll
            for (int f=0; f<16; f++) {
                float wv = wsh[e*16+f];
                a.x += wv*x[f].x; a.y += wv*x[f].y; a.z += wv*x[f].z; a.w += wv*x[f].w;
            }
            half4 hv; hv[0]=(Hh)a.x; hv[1]=(Hh)a.y; hv[2]=(Hh)a.z; hv[3]=(Hh)a.w;
            *(half4*)(dst + (size_t)(b*16+e)*ND_ + (size_t)r*4) = hv;
        }
    } else if (bid < 768) {
        __shared__ Hh tile[64*48];            // [d][j], stride 48 halves
        int tb = bid - 512;                   // 0..255
        int be = tb >> 3;                     // 0..31
        int jtg = tb & 7;
        const float4* v4 = (const float4*)v;
        for (int u=0; u<8; u++) {
            int jt = jtg*8 + u;               // 0..63
            #pragma unroll
            for (int p=0; p<2; p++) {
                int j = p*16 + (tid>>4);
                int d4 = tid & 15;
                float4 val = v4[(size_t)be*32768 + (size_t)(jt*32+j)*16 + d4];
                tile[(d4*4+0)*48 + j] = (Hh)val.x;
                tile[(d4*4+1)*48 + j] = (Hh)val.y;
                tile[(d4*4+2)*48 + j] = (Hh)val.z;
                tile[(d4*4+3)*48 + j] = (Hh)val.w;
            }
            __syncthreads();
            {
                int d = tid >> 2;
                int jc = (tid & 3) * 8;
                half8 o;
                #pragma unroll
                for (int z=0; z<8; z++) o[z] = tile[d*48 + jc + z];
                *(half8*)(vt2 + ((size_t)(be*64) + jt)*2048 + (size_t)tid*8) = o;
            }
            __syncthreads();
        }
    } else {
        // zero out + lacc. out = 2*16*2048*64 floats = 1048576 float4.
        int zid = (bid - 768) * 256 + tid;    // 0 .. 262143
        float4 zz = make_float4(0.f,0.f,0.f,0.f);
        #pragma unroll
        for (int u=0; u<4; u++) out4[(size_t)u*262144 + zid] = zz;
        if (zid < 16384) lacc4[zid] = zz;
    }
}

// ---------------------------------------------------------------------------
// K2: denominators. LDS-free, barrier-free, slabs jt ≡ s (mod 8); XCD-aligned
// already (s = bid&7 = bid%8 = XCD). 512 thr / 8 waves; wave w owns
// f={2w,2w+1}; i-tile 32. (R6 verbatim)
// ---------------------------------------------------------------------------
__global__ __launch_bounds__(512) void denom_kernel(const Hh* __restrict__ qb,
    const Hh* __restrict__ kb, float* __restrict__ lacc_g)
{
    int bid = blockIdx.x;
    int s = bid & 7;
    int idx = 127 - (bid >> 3);
    int b = idx & 1, it = idx >> 1;          // it 0..63
    if (s > it) return;

    int i0 = it * 32;
    int tid = threadIdx.x;
    int lane = tid & 63, w = tid >> 6;
    int qd = lane >> 4, c = lane & 15;
    int f0 = 2*w;

    half8 aq[2][2][2];
    #pragma unroll
    for (int fi=0; fi<2; fi++) {
        #pragma unroll
        for (int ig=0; ig<2; ig++) {
            const Hh* qr = qb + (size_t)((b*16+f0+fi)*N_ + i0 + ig*16 + c)*64 + qd*8;
            aq[fi][ig][0] = *(const half8*)qr;
            aq[fi][ig][1] = *(const half8*)(qr+32);
        }
    }
    float lacc[2][2][4];
    #pragma unroll
    for (int fi=0;fi<2;fi++) for (int ig=0;ig<2;ig++) for (int r=0;r<4;r++) lacc[fi][ig][r]=0.f;

    for (int jt = s; jt <= it; jt += 8) {
        int j0 = jt*32;
        #pragma unroll
        for (int fi=0; fi<2; fi++) {
            #pragma unroll
            for (int jh=0; jh<2; jh++) {
                const Hh* kr = kb + (size_t)((b*16+f0+fi)*N_ + j0 + jh*16 + c)*64 + qd*8;
                half8 b0 = *(const half8*)kr;
                half8 b1 = *(const half8*)(kr+32);
                #pragma unroll
                for (int ig=0; ig<2; ig++) {
                    float4v sv = {0.f,0.f,0.f,0.f};
                    sv = __builtin_amdgcn_mfma_f32_16x16x32_f16(aq[fi][ig][0], b0, sv, 0,0,0);
                    sv = __builtin_amdgcn_mfma_f32_16x16x32_f16(aq[fi][ig][1], b1, sv, 0,0,0);
                    #pragma unroll
                    for (int r=0; r<4; r++) {
                        int i = i0 + ig*16 + qd*4 + r;
                        int j = j0 + jh*16 + c;
                        float ev = (j <= i) ? __builtin_amdgcn_exp2f(sv[r]*C1) : 0.f;
                        lacc[fi][ig][r] += ev;
                    }
                }
            }
        }
    }
    #pragma unroll
    for (int fi=0; fi<2; fi++) {
        #pragma unroll
        for (int ig=0; ig<2; ig++) {
            #pragma unroll
            for (int r=0; r<4; r++) {
                float vs = lacc[fi][ig][r];
                vs += __shfl_xor(vs, 1);
                vs += __shfl_xor(vs, 2);
                vs += __shfl_xor(vs, 4);
                vs += __shfl_xor(vs, 8);
                if (c == 0)
                    unsafeAtomicAdd(&lacc_g[(size_t)(b*16+f0+fi)*N_ + i0 + ig*16 + qd*4 + r], vs);
            }
        }
    }
}

// ---------------------------------------------------------------------------
// K3: main fused pass (R6 inner structure, grid/work identical to R6).
// DELTA vs R6: bid remap so slab s = (bid%8)>>1 -> each XCD PAIR serves one
// j-slab (~4 MB K+V slice fits its L2); epilogue nc order rotated by s to
// stagger atomic RMW line-bouncing. 512 thr / 8 waves; i-tile 16, j-tile 32,
// slabs mod 4; 39.3 KB LDS -> 4 blocks/CU.
// ---------------------------------------------------------------------------
__global__ __launch_bounds__(512,4) void attend_kernel(const Hh* __restrict__ qb,
    const Hh* __restrict__ kb, const Hh* __restrict__ vt2,
    const float* __restrict__ lacc_g, const float* __restrict__ Wpost,
    float* __restrict__ out)
{
    __shared__ Hh Ebuf[32*EB_JS];   // 20736 B
    __shared__ Hh Pm[16*PM_ES];     // 18560 B

    int bid = blockIdx.x;
    int s = (bid & 7) >> 1;                  // slab 0..3, tied to XCD pair
    int idxp = ((bid >> 3) << 1) | (bid & 1);// 0..255, bijective with (bid)
    int idx = 255 - idxp;
    int b = idx & 1, it = idx >> 1;          // it 0..127
    int jtmax = it >> 1;                     // last 32-j tile
    if (s > jtmax) return;
    int i0 = it * 16;

    int tid = threadIdx.x;
    int lane = tid & 63, w = tid >> 6;
    int qd = lane >> 4, c = lane & 15;

    // ---- scores role: wave w -> f-group fg=w&3 (f=4fg..4fg+3), j-chunk jh=w>>2
    int fg = w & 3, jh = w >> 2;
    half8 aq[4][2];
    float lgr[4][4];
    #pragma unroll
    for (int ff=0; ff<4; ff++) {
        int f = 4*fg + ff;
        const Hh* qr = qb + (size_t)((b*16+f)*N_ + i0 + c)*64 + qd*8;
        aq[ff][0] = *(const half8*)qr;
        aq[ff][1] = *(const half8*)(qr+32);
        #pragma unroll
        for (int r=0; r<4; r++)
            lgr[ff][r] = __builtin_amdgcn_logf(
                lacc_g[(size_t)(b*16+f)*N_ + i0 + qd*4 + r]);
    }
    // ---- mix role: wave w -> jh2=w&1, i in [4*(w>>1), +4)
    int jh2 = w & 1, ib = 4*(w>>1);
    half4 wf;   // B[k=f=qd*4+z][n=e=c] = Wpost[e][f]
    #pragma unroll
    for (int z=0; z<4; z++) wf[z] = (Hh)Wpost[c*16 + qd*4 + z];

    float4v acc[2][4];
    #pragma unroll
    for (int el=0; el<2; el++) for (int nc=0; nc<4; nc++)
        acc[el][nc] = (float4v){0.f,0.f,0.f,0.f};

    auto scores = [&](int jt) {
        int jc = jt*32 + jh*16;
        float4v sv[4];
        #pragma unroll
        for (int ff=0; ff<4; ff++) {
            int f = 4*fg + ff;
            const Hh* kr = kb + (size_t)((b*16+f)*N_ + jc + c)*64 + qd*8;
            half8 b0 = *(const half8*)kr;
            half8 b1 = *(const half8*)(kr+32);
            float4v t = {0.f,0.f,0.f,0.f};
            t = __builtin_amdgcn_mfma_f32_16x16x32_f16(aq[ff][0], b0, t, 0,0,0);
            t = __builtin_amdgcn_mfma_f32_16x16x32_f16(aq[ff][1], b1, t, 0,0,0);
            sv[ff] = t;
        }
        int j = jc + c;
        #pragma unroll
        for (int r=0; r<4; r++) {
            int i = i0 + qd*4 + r;
            half4 h;
            #pragma unroll
            for (int ff=0; ff<4; ff++)
                h[ff] = (Hh)((j <= i) ? __builtin_amdgcn_exp2f(sv[ff][r]*C1 - lgr[ff][r]) : 0.f);
            *(half4*)&Ebuf[(jh*16+c)*EB_JS + (qd*4+r)*EB_IS + fg*4] = h;
        }
    };

    scores(s);
    __syncthreads();

    for (int jt = s; jt <= jtmax; jt += 4) {
        // ---- head mix: Pm[j,e] for this wave's (jh2, i-quad) ----
        #pragma unroll
        for (int ii=0; ii<4; ii++) {
            int i = ib + ii;
            half4 ef = *(const half4*)&Ebuf[(jh2*16+c)*EB_JS + i*EB_IS + qd*4];
            float4v cc = {0.f,0.f,0.f,0.f};
            cc = __builtin_amdgcn_mfma_f32_16x16x16f16(ef, wf, cc, 0,0,0);
            // D[m=j=qd*4+r][n=e=c] -> pack half4 over j
            half4 hv;
            #pragma unroll
            for (int r=0; r<4; r++) hv[r] = (Hh)cc[r];
            *(half4*)&Pm[c*PM_ES + i*PM_IS + jh2*16 + qd*4] = hv;
        }
        __syncthreads();
        // ---- PV(jt), overlapped with scores(jt+4) ----
        #pragma unroll
        for (int el=0; el<2; el++) {
            int e = 2*w + el;
            half8 pa = *(const half8*)&Pm[e*PM_ES + c*PM_IS + qd*8];
            #pragma unroll
            for (int nc=0; nc<4; nc++) {
                const Hh* vr = vt2 + (size_t)((b*16+e)*64 + jt)*2048 + (nc*16+c)*32 + qd*8;
                half8 vb = *(const half8*)vr;
                acc[el][nc] = __builtin_amdgcn_mfma_f32_16x16x32_f16(pa, vb, acc[el][nc], 0,0,0);
            }
        }
        if (jt + 4 <= jtmax) scores(jt + 4);
        __syncthreads();
    }

    // ---- accumulate partial O (nc order rotated by slab to stagger RMW) ----
    #pragma unroll
    for (int el=0; el<2; el++) {
        int e = 2*w + el;
        #pragma unroll
        for (int nc0=0; nc0<4; nc0++) {
            int nc = (nc0 + s) & 3;
            #pragma unroll
            for (int r=0; r<4; r++)
                unsafeAtomicAdd(&out[(size_t)((b*16+e)*N_ + i0 + qd*4 + r)*64 + nc*16 + c],
                                acc[el][nc][r]);
        }
    }
}

extern "C" void kernel_launch(void* const* d_in, const int* in_sizes, int n_in,
                              void* d_out, int out_size, void* d_ws, size_t ws_size,
                              hipStream_t stream) {
    const float* q     = (const float*)d_in[0];
    const float* k     = (const float*)d_in[1];
    const float* v     = (const float*)d_in[2];
    const float* Wpre  = (const float*)d_in[3];
    const float* Wpost = (const float*)d_in[4];
    float* out = (float*)d_out;

    size_t tsz = (size_t)B_*H_*N_*D_;       // 4 Mi halves = 8 MB each
    Hh* qb = (Hh*)d_ws;
    Hh* kb = qb + tsz;
    Hh* vt2 = kb + tsz;
    float* lacc = (float*)(vt2 + tsz);      // 24 MB offset, 256 KB

    prep_kernel<<<1792, 256, 0, stream>>>(q, k, v, Wpre, qb, kb, vt2,
                                          (float4*)out, (float4*)lacc);
    denom_kernel<<<1024, 512, 0, stream>>>(qb, kb, lacc);
    attend_kernel<<<1024, 512, 0, stream>>>(qb, kb, vt2, lacc, Wpost, out);
}

// Round 10
// 264.941 us; speedup vs baseline: 1.1861x; 1.0009x over previous
//
#include <hip/hip_runtime.h>
#include <math.h>

typedef _Float16 Hh;
typedef __attribute__((ext_vector_type(8))) _Float16 half8;
typedef __attribute__((ext_vector_type(4))) _Float16 half4;
typedef __attribute__((ext_vector_type(4))) float float4v;

#define B_ 2
#define H_ 16
#define N_ 2048
#define D_ 64
#define ND_ (N_*D_)
#define C1 0.04508422f   // (1/32)*log2(e); softmax in base-2 throughout

// Barrier WITHOUT the vmcnt(0) drain __syncthreads would emit: LDS
// produce/consume only needs lgkmcnt(0); in-flight global loads (prefetched
// K/V for the next tile) stay outstanding across the barrier and are waited
// on by the compiler's automatic vmcnt before their MFMA use.
#define BAR() asm volatile("s_waitcnt lgkmcnt(0)\n\ts_barrier" ::: "memory")

// Ebuf: [j(32)][i(16)][f(16+4pad)]  j-stride 324, i-stride 20 halves
#define EB_JS 324
#define EB_IS 20
// Pm: [e(16)][i(16)][j(32+4pad)]    e-stride 580, i-stride 36 halves
#define PM_ES 580
#define PM_IS 36

// ---------------------------------------------------------------------------
// K1: prep.
//  blocks [0,512):    premix q,k with W_pre -> f16 qb/kb [b][e][n][d]
//  blocks [512,768):  transpose v -> f16 vt2, tile-blocked [be][jt][d][j&31]
//  blocks [768,1792): zero out (16.8 MB) and lacc (256 KB) — replaces memsets
// ---------------------------------------------------------------------------
__global__ __launch_bounds__(256) void prep_kernel(const float* __restrict__ q,
    const float* __restrict__ k, const float* __restrict__ v,
    const float* __restrict__ Wpre,
    Hh* __restrict__ qb, Hh* __restrict__ kb, Hh* __restrict__ vt2,
    float4* __restrict__ out4, float4* __restrict__ lacc4)
{
    int tid = threadIdx.x;
    int bid = blockIdx.x;
    if (bid < 512) {
        __shared__ float wsh[256];
        wsh[tid] = Wpre[tid];
        __syncthreads();
        int tensor = bid >> 8;
        int g = ((bid & 255) << 8) | tid;     // 0 .. 65535
        int b = g >> 15;
        int r = g & 32767;                    // (n,d4): n*16 + d4
        const float4* src = (const float4*)(tensor ? k : q);
        Hh* dst = tensor ? kb : qb;
        float4 x[16];
        #pragma unroll
        for (int f=0; f<16; f++) x[f] = src[(size_t)(b*16+f)*32768 + r];
        #pragma unroll
        for (int e=0; e<16; e++) {
            float4 a = make_float4(0.f,0.f,0.f,0.f);
            #pragma unroll
            for (int f=0; f<16; f++) {
                float wv = wsh[e*16+f];
                a.x += wv*x[f].x; a.y += wv*x[f].y; a.z += wv*x[f].z; a.w += wv*x[f].w;
            }
            half4 hv; hv[0]=(Hh)a.x; hv[1]=(Hh)a.y; hv[2]=(Hh)a.z; hv[3]=(Hh)a.w;
            *(half4*)(dst + (size_t)(b*16+e)*ND_ + (size_t)r*4) = hv;
        }
    } else if (bid < 768) {
        __shared__ Hh tile[64*48];            // [d][j], stride 48 halves
        int tb = bid - 512;                   // 0..255
        int be = tb >> 3;                     // 0..31
        int jtg = tb & 7;
        const float4* v4 = (const float4*)v;
        for (int u=0; u<8; u++) {
            int jt = jtg*8 + u;               // 0..63
            #pragma unroll
            for (int p=0; p<2; p++) {
                int j = p*16 + (tid>>4);
                int d4 = tid & 15;
                float4 val = v4[(size_t)be*32768 + (size_t)(jt*32+j)*16 + d4];
                tile[(d4*4+0)*48 + j] = (Hh)val.x;
                tile[(d4*4+1)*48 + j] = (Hh)val.y;
                tile[(d4*4+2)*48 + j] = (Hh)val.z;
                tile[(d4*4+3)*48 + j] = (Hh)val.w;
            }
            BAR();
            {
                int d = tid >> 2;
                int jc = (tid & 3) * 8;
                half8 o;
                #pragma unroll
                for (int z=0; z<8; z++) o[z] = tile[d*48 + jc + z];
                *(half8*)(vt2 + ((size_t)(be*64) + jt)*2048 + (size_t)tid*8) = o;
            }
            BAR();
        }
    } else {
        // zero out + lacc. out = 2*16*2048*64 floats = 1048576 float4.
        int zid = (bid - 768) * 256 + tid;    // 0 .. 262143
        float4 zz = make_float4(0.f,0.f,0.f,0.f);
        #pragma unroll
        for (int u=0; u<4; u++) out4[(size_t)u*262144 + zid] = zz;
        if (zid < 16384) lacc4[zid] = zz;
    }
}

// ---------------------------------------------------------------------------
// K2: denominators. LDS-free, barrier-free, slabs jt ≡ s (mod 8). 512 thr /
// 8 waves; wave w owns f={2w,2w+1}; i-tile 32. (R6 verbatim)
// ---------------------------------------------------------------------------
__global__ __launch_bounds__(512) void denom_kernel(const Hh* __restrict__ qb,
    const Hh* __restrict__ kb, float* __restrict__ lacc_g)
{
    int bid = blockIdx.x;
    int s = bid & 7;
    int idx = 127 - (bid >> 3);
    int b = idx & 1, it = idx >> 1;          // it 0..63
    if (s > it) return;

    int i0 = it * 32;
    int tid = threadIdx.x;
    int lane = tid & 63, w = tid >> 6;
    int qd = lane >> 4, c = lane & 15;
    int f0 = 2*w;

    half8 aq[2][2][2];
    #pragma unroll
    for (int fi=0; fi<2; fi++) {
        #pragma unroll
        for (int ig=0; ig<2; ig++) {
            const Hh* qr = qb + (size_t)((b*16+f0+fi)*N_ + i0 + ig*16 + c)*64 + qd*8;
            aq[fi][ig][0] = *(const half8*)qr;
            aq[fi][ig][1] = *(const half8*)(qr+32);
        }
    }
    float lacc[2][2][4];
    #pragma unroll
    for (int fi=0;fi<2;fi++) for (int ig=0;ig<2;ig++) for (int r=0;r<4;r++) lacc[fi][ig][r]=0.f;

    for (int jt = s; jt <= it; jt += 8) {
        int j0 = jt*32;
        #pragma unroll
        for (int fi=0; fi<2; fi++) {
            #pragma unroll
            for (int jh=0; jh<2; jh++) {
                const Hh* kr = kb + (size_t)((b*16+f0+fi)*N_ + j0 + jh*16 + c)*64 + qd*8;
                half8 b0 = *(const half8*)kr;
                half8 b1 = *(const half8*)(kr+32);
                #pragma unroll
                for (int ig=0; ig<2; ig++) {
                    float4v sv = {0.f,0.f,0.f,0.f};
                    sv = __builtin_amdgcn_mfma_f32_16x16x32_f16(aq[fi][ig][0], b0, sv, 0,0,0);
                    sv = __builtin_amdgcn_mfma_f32_16x16x32_f16(aq[fi][ig][1], b1, sv, 0,0,0);
                    #pragma unroll
                    for (int r=0; r<4; r++) {
                        int i = i0 + ig*16 + qd*4 + r;
                        int j = j0 + jh*16 + c;
                        float ev = (j <= i) ? __builtin_amdgcn_exp2f(sv[r]*C1) : 0.f;
                        lacc[fi][ig][r] += ev;
                    }
                }
            }
        }
    }
    #pragma unroll
    for (int fi=0; fi<2; fi++) {
        #pragma unroll
        for (int ig=0; ig<2; ig++) {
            #pragma unroll
            for (int r=0; r<4; r++) {
                float vs = lacc[fi][ig][r];
                vs += __shfl_xor(vs, 1);
                vs += __shfl_xor(vs, 2);
                vs += __shfl_xor(vs, 4);
                vs += __shfl_xor(vs, 8);
                if (c == 0)
                    unsafeAtomicAdd(&lacc_g[(size_t)(b*16+f0+fi)*N_ + i0 + ig*16 + qd*4 + r], vs);
            }
        }
    }
}

// ---------------------------------------------------------------------------
// K3: main fused pass (R9 structure; ONLY change: BAR() instead of
// __syncthreads — no vmcnt drain, prefetched K/V loads stay in flight
// across barriers). 512 thr / 8 waves; i-tile 16, j-tile 32, slabs mod 4;
// 39.3 KB LDS -> 4 blocks/CU (= 32-wave cap).
// ---------------------------------------------------------------------------
__global__ __launch_bounds__(512,4) void attend_kernel(const Hh* __restrict__ qb,
    const Hh* __restrict__ kb, const Hh* __restrict__ vt2,
    const float* __restrict__ lacc_g, const float* __restrict__ Wpost,
    float* __restrict__ out)
{
    __shared__ Hh Ebuf[32*EB_JS];   // 20736 B
    __shared__ Hh Pm[16*PM_ES];     // 18560 B

    int bid = blockIdx.x;
    int s = (bid & 7) >> 1;                  // slab 0..3, tied to XCD pair
    int idxp = ((bid >> 3) << 1) | (bid & 1);// 0..255, bijective with (bid)
    int idx = 255 - idxp;
    int b = idx & 1, it = idx >> 1;          // it 0..127
    int jtmax = it >> 1;                     // last 32-j tile
    if (s > jtmax) return;
    int i0 = it * 16;

    int tid = threadIdx.x;
    int lane = tid & 63, w = tid >> 6;
    int qd = lane >> 4, c = lane & 15;

    // ---- scores role: wave w -> f-group fg=w&3 (f=4fg..4fg+3), j-chunk jh=w>>2
    int fg = w & 3, jh = w >> 2;
    half8 aq[4][2];
    float lgr[4][4];
    #pragma unroll
    for (int ff=0; ff<4; ff++) {
        int f = 4*fg + ff;
        const Hh* qr = qb + (size_t)((b*16+f)*N_ + i0 + c)*64 + qd*8;
        aq[ff][0] = *(const half8*)qr;
        aq[ff][1] = *(const half8*)(qr+32);
        #pragma unroll
        for (int r=0; r<4; r++)
            lgr[ff][r] = __builtin_amdgcn_logf(
                lacc_g[(size_t)(b*16+f)*N_ + i0 + qd*4 + r]);
    }
    // ---- mix role: wave w -> jh2=w&1, i in [4*(w>>1), +4)
    int jh2 = w & 1, ib = 4*(w>>1);
    half4 wf;   // B[k=f=qd*4+z][n=e=c] = Wpost[e][f]
    #pragma unroll
    for (int z=0; z<4; z++) wf[z] = (Hh)Wpost[c*16 + qd*4 + z];

    float4v acc[2][4];
    #pragma unroll
    for (int el=0; el<2; el++) for (int nc=0; nc<4; nc++)
        acc[el][nc] = (float4v){0.f,0.f,0.f,0.f};

    auto scores = [&](int jt) {
        int jc = jt*32 + jh*16;
        float4v sv[4];
        #pragma unroll
        for (int ff=0; ff<4; ff++) {
            int f = 4*fg + ff;
            const Hh* kr = kb + (size_t)((b*16+f)*N_ + jc + c)*64 + qd*8;
            half8 b0 = *(const half8*)kr;
            half8 b1 = *(const half8*)(kr+32);
            float4v t = {0.f,0.f,0.f,0.f};
            t = __builtin_amdgcn_mfma_f32_16x16x32_f16(aq[ff][0], b0, t, 0,0,0);
            t = __builtin_amdgcn_mfma_f32_16x16x32_f16(aq[ff][1], b1, t, 0,0,0);
            sv[ff] = t;
        }
        int j = jc + c;
        #pragma unroll
        for (int r=0; r<4; r++) {
            int i = i0 + qd*4 + r;
            half4 h;
            #pragma unroll
            for (int ff=0; ff<4; ff++)
                h[ff] = (Hh)((j <= i) ? __builtin_amdgcn_exp2f(sv[ff][r]*C1 - lgr[ff][r]) : 0.f);
            *(half4*)&Ebuf[(jh*16+c)*EB_JS + (qd*4+r)*EB_IS + fg*4] = h;
        }
    };

    scores(s);
    BAR();

    for (int jt = s; jt <= jtmax; jt += 4) {
        // ---- head mix: Pm[j,e] for this wave's (jh2, i-quad) ----
        #pragma unroll
        for (int ii=0; ii<4; ii++) {
            int i = ib + ii;
            half4 ef = *(const half4*)&Ebuf[(jh2*16+c)*EB_JS + i*EB_IS + qd*4];
            float4v cc = {0.f,0.f,0.f,0.f};
            cc = __builtin_amdgcn_mfma_f32_16x16x16f16(ef, wf, cc, 0,0,0);
            // D[m=j=qd*4+r][n=e=c] -> pack half4 over j
            half4 hv;
            #pragma unroll
            for (int r=0; r<4; r++) hv[r] = (Hh)cc[r];
            *(half4*)&Pm[c*PM_ES + i*PM_IS + jh2*16 + qd*4] = hv;
        }
        BAR();
        // ---- PV(jt), overlapped with scores(jt+4); loads stay in flight ----
        #pragma unroll
        for (int el=0; el<2; el++) {
            int e = 2*w + el;
            half8 pa = *(const half8*)&Pm[e*PM_ES + c*PM_IS + qd*8];
            #pragma unroll
            for (int nc=0; nc<4; nc++) {
                const Hh* vr = vt2 + (size_t)((b*16+e)*64 + jt)*2048 + (nc*16+c)*32 + qd*8;
                half8 vb = *(const half8*)vr;
                acc[el][nc] = __builtin_amdgcn_mfma_f32_16x16x32_f16(pa, vb, acc[el][nc], 0,0,0);
            }
        }
        if (jt + 4 <= jtmax) scores(jt + 4);
        BAR();
    }

    // ---- accumulate partial O (nc order rotated by slab to stagger RMW) ----
    #pragma unroll
    for (int el=0; el<2; el++) {
        int e = 2*w + el;
        #pragma unroll
        for (int nc0=0; nc0<4; nc0++) {
            int nc = (nc0 + s) & 3;
            #pragma unroll
            for (int r=0; r<4; r++)
                unsafeAtomicAdd(&out[(size_t)((b*16+e)*N_ + i0 + qd*4 + r)*64 + nc*16 + c],
                                acc[el][nc][r]);
        }
    }
}

extern "C" void kernel_launch(void* const* d_in, const int* in_sizes, int n_in,
                              void* d_out, int out_size, void* d_ws, size_t ws_size,
                              hipStream_t stream) {
    const float* q     = (const float*)d_in[0];
    const float* k     = (const float*)d_in[1];
    const float* v     = (const float*)d_in[2];
    const float* Wpre  = (const float*)d_in[3];
    const float* Wpost = (const float*)d_in[4];
    float* out = (float*)d_out;

    size_t tsz = (size_t)B_*H_*N_*D_;       // 4 Mi halves = 8 MB each
    Hh* qb = (Hh*)d_ws;
    Hh* kb = qb + tsz;
    Hh* vt2 = kb + tsz;
    float* lacc = (float*)(vt2 + tsz);      // 24 MB offset, 256 KB

    prep_kernel<<<1792, 256, 0, stream>>>(q, k, v, Wpre, qb, kb, vt2,
                                          (float4*)out, (float4*)lacc);
    denom_kernel<<<1024, 512, 0, stream>>>(qb, kb, lacc);
    attend_kernel<<<1024, 512, 0, stream>>>(qb, kb, vt2, lacc, Wpost, out);
}